// Round 3
// baseline (226.420 us; speedup 1.0000x reference)
//
#include <hip/hip_runtime.h>

// Problem constants (match reference)
#define B 32
#define S 32
#define N 128
#define U 64
#define E 2
#define NCLS 5

// R10: occupancy 2->4 waves/SIMD. R8 (DS->readlane) and R9 (drop LDS/barrier)
// were both neutral => k_step is not pipe-bound, it's LATENCY-bound: three
// dependent phases of ~500 L1/L2 loads per wave with only 2 waves/SIMD (grid
// 512 = 2 blocks/CU) to hide ~200-300cyc L2 latency. VALU floor ~3.5us/step
// and L2 BW ~25% utilized -- headroom on both. Fix: 1 row per wave -> grid
// 1024 blocks (B*32) = 4 blocks/CU = 16 waves/CU = 4 waves/SIMD. Weight L2
// traffic doubles (~17 TB/s agg, still < 34.5 ceiling); latency hiding 2x.
// Per-row FMA order identical to R9 -> bit-identical h; LAST tail reduces 32
// partials (max reassociation exact).
//
// Each block: 4 rows of one batch (4 waves x 1 row); lane = feature column.

__device__ __forceinline__ float sigmoid_f(float x) {
    return __fdividef(1.f, 1.f + __expf(-x));
}
__device__ __forceinline__ float tanh_f(float x) {
    float t = __expf(-2.f * fabsf(x));
    float y = __fdividef(1.f - t, 1.f + t);
    return copysignf(y, x);
}
// broadcast lane u's value of v to all lanes (VALU pipe, no LDS)
__device__ __forceinline__ float bcast(float v, int u) {
    return __uint_as_float(__builtin_amdgcn_readlane(__float_as_uint(v), u));
}

template <int FIRST, int LAST>
__global__ __launch_bounds__(256, 4) void k_step(
    const float* __restrict__ x, const int* __restrict__ lens,
    const float* __restrict__ hin, float* __restrict__ hout,
    const float* __restrict__ A, const float* __restrict__ Wmsg,
    const float* __restrict__ bmsg, const float* __restrict__ Wg,
    const float* __restrict__ Ug, const float* __restrict__ bg,
    const float* __restrict__ fcw, float* __restrict__ partial, int l) {
    __shared__ float red[4 * NCLS];  // only used in LAST tail reduce (80 B)
    int tid = threadIdx.x;
    int wave = tid >> 6, lane = tid & 63;
    int b = blockIdx.x >> 5;
    int j = blockIdx.x & 31;
    // wave-uniform row; readfirstlane keeps A-row addresses scalar-provable
    int row = __builtin_amdgcn_readfirstlane(j * 4 + wave);

    // h source: global, no staging (h[b]=32KB, L1/L2-resident, shared by all
    // 32 blocks of this batch).
    const float* __restrict__ hsrc;
    if (FIRST) {
        int idx = lens[b] - 1;
        idx = idx < 0 ? 0 : (idx > S - 1 ? S - 1 : idx);
        hsrc = x + (size_t)(b * S + idx) * N * U;
    } else {
        hsrc = hin + (size_t)b * N * U;
    }

    float hv = hsrc[row * U + lane];

    // ---- aggregate: s_e = sum_m A[b,e,row,m] * h[m][lane]
    float s0 = 0.f, s1 = 0.f;
    {
        const float4* A0 = (const float4*)(A + (((size_t)b * E + 0) * N + row) * N);
        const float4* A1 = (const float4*)(A + (((size_t)b * E + 1) * N + row) * N);
#pragma unroll 8
        for (int m4 = 0; m4 < N / 4; ++m4) {
            float4 a0 = A0[m4], a1 = A1[m4];
            float q0 = hsrc[(m4 * 4 + 0) * U + lane];
            float q1 = hsrc[(m4 * 4 + 1) * U + lane];
            float q2 = hsrc[(m4 * 4 + 2) * U + lane];
            float q3 = hsrc[(m4 * 4 + 3) * U + lane];
            s0 = fmaf(a0.x, q0, s0); s0 = fmaf(a0.y, q1, s0);
            s0 = fmaf(a0.z, q2, s0); s0 = fmaf(a0.w, q3, s0);
            s1 = fmaf(a1.x, q0, s1); s1 = fmaf(a1.y, q1, s1);
            s1 = fmaf(a1.z, q2, s1); s1 = fmaf(a1.w, q3, s1);
        }
    }

    // ---- a = sum_e s_e @ Wmsg[l][e] + bmsg[l]  (readlane bcast)
    // Two separate edge loops keep the exact accumulation order.
    float av = bmsg[l * U + lane];
    {
        const float* W0 = Wmsg + (size_t)(l * E + 0) * U * U + lane;
        const float* W1 = W0 + U * U;
#pragma unroll 16
        for (int u = 0; u < U; ++u) {
            av = fmaf(bcast(s0, u), W0[u * U], av);
        }
#pragma unroll 16
        for (int u = 0; u < U; ++u) {
            av = fmaf(bcast(s1, u), W1[u * U], av);
        }
    }

    // ---- gate matmuls (lane = output column v); a,h broadcast via readlane
    const float* Wg0 = Wg + (size_t)l * 3 * U * U + lane;
    const float* Wg1 = Wg0 + U * U;
    const float* Wg2 = Wg1 + U * U;
    const float* Ug0 = Ug + (size_t)l * 3 * U * U + lane;
    const float* Ug1 = Ug0 + U * U;
    const float* Ug2 = Ug1 + U * U;
    float accz = bg[(l * 3 + 0) * U + lane];
    float accr = bg[(l * 3 + 1) * U + lane];
    float accc = bg[(l * 3 + 2) * U + lane];
#pragma unroll 16
    for (int u = 0; u < U; ++u) {
        float w0 = Wg0[u * U], w1 = Wg1[u * U], w2 = Wg2[u * U];
        float g0 = Ug0[u * U], g1 = Ug1[u * U];
        float a = bcast(av, u);
        float h = bcast(hv, u);
        accz = fmaf(a, w0, accz); accz = fmaf(h, g0, accz);
        accr = fmaf(a, w1, accr); accr = fmaf(h, g1, accr);
        accc = fmaf(a, w2, accc);
    }
    float rg = sigmoid_f(accr);
    float rh = rg * hv;
#pragma unroll 16
    for (int u = 0; u < U; ++u) {
        accc = fmaf(bcast(rh, u), Ug2[u * U], accc);
    }
    float zg = sigmoid_f(accz);
    float hn = (1.f - zg) * hv + zg * tanh_f(accc);

    if (!LAST) {
        hout[((size_t)b * N + row) * U + lane] = hn;
    } else {
        // fused classification partial: max over our 4 rows of relu(h')@fc_w
        float lg[NCLS];
        float rv = hn > 0.f ? hn : 0.f;
#pragma unroll
        for (int c = 0; c < NCLS; c++) {
            lg[c] = rv * fcw[lane * NCLS + c];
        }
#pragma unroll
        for (int off = 32; off; off >>= 1) {
#pragma unroll
            for (int c = 0; c < NCLS; c++) {
                lg[c] += __shfl_xor(lg[c], off, 64);
            }
        }
        if (lane == 0) {
#pragma unroll
            for (int c = 0; c < NCLS; c++) red[wave * NCLS + c] = lg[c];
        }
        __syncthreads();  // only barrier in the kernel: cross-wave max reduce
        if (tid < NCLS) {
            float m = red[tid];
            for (int w = 1; w < 4; ++w) m = fmaxf(m, red[w * NCLS + tid]);
            partial[(size_t)(b * 32 + j) * NCLS + tid] = m;
        }
    }
}

// ---------------------------------------------------------------------------
// k_final: out[b][c] = max over 32 block-partials + fc_b
__global__ void k_final(const float* __restrict__ partial, const float* __restrict__ fcb,
                        float* __restrict__ out) {
    int b = blockIdx.x, c = threadIdx.x;
    if (c < NCLS) {
        float m = -3.4e38f;
        for (int jj = 0; jj < 32; ++jj)
            m = fmaxf(m, partial[(size_t)(b * 32 + jj) * NCLS + c]);
        out[b * NCLS + c] = m + fcb[c];
    }
}

// ---------------------------------------------------------------------------
extern "C" void kernel_launch(void* const* d_in, const int* in_sizes, int n_in,
                              void* d_out, int out_size, void* d_ws, size_t ws_size,
                              hipStream_t stream) {
    const float* x    = (const float*)d_in[0];
    const int*   lens = (const int*)d_in[1];
    const float* A    = (const float*)d_in[2];
    const float* Wmsg = (const float*)d_in[3];
    const float* bmsg = (const float*)d_in[4];
    const float* Wg   = (const float*)d_in[5];
    const float* Ug   = (const float*)d_in[6];
    const float* bg   = (const float*)d_in[7];
    const float* fcw  = (const float*)d_in[8];
    const float* fcb  = (const float*)d_in[9];
    float* out = (float*)d_out;

    float* hA      = (float*)d_ws;                   // [B][N][U]
    float* hB      = hA + (size_t)B * N * U;         // [B][N][U]
    float* partial = hB + (size_t)B * N * U;         // [B][32][NCLS]

    // steps 0-2: layer 0; steps 3-5: layer 1
    k_step<1, 0><<<B * 32, 256, 0, stream>>>(x, lens, nullptr, hA, A, Wmsg, bmsg, Wg, Ug, bg, fcw, partial, 0);
    k_step<0, 0><<<B * 32, 256, 0, stream>>>(x, lens, hA, hB, A, Wmsg, bmsg, Wg, Ug, bg, fcw, partial, 0);
    k_step<0, 0><<<B * 32, 256, 0, stream>>>(x, lens, hB, hA, A, Wmsg, bmsg, Wg, Ug, bg, fcw, partial, 0);
    k_step<0, 0><<<B * 32, 256, 0, stream>>>(x, lens, hA, hB, A, Wmsg, bmsg, Wg, Ug, bg, fcw, partial, 1);
    k_step<0, 0><<<B * 32, 256, 0, stream>>>(x, lens, hB, hA, A, Wmsg, bmsg, Wg, Ug, bg, fcw, partial, 1);
    k_step<0, 1><<<B * 32, 256, 0, stream>>>(x, lens, hA, hB, A, Wmsg, bmsg, Wg, Ug, bg, fcw, partial, 1);
    k_final<<<B, 64, 0, stream>>>(partial, fcb, out);
}